// Round 1
// baseline (224.155 us; speedup 1.0000x reference)
//
#include <hip/hip_runtime.h>
#include <hip/hip_bf16.h>
#include <math.h>

#define B 4
#define TQ 512
#define TV 1024
#define DQ 256
#define DV 256
#define UNITS 64
#define QBLK 4

// tanh(x) = 1 - 2/(exp(2x)+1); saturates correctly for |x| large, no branches.
__device__ __forceinline__ float tanh_fast(float x) {
    float e = __expf(2.0f * x);                    // v_mul + v_exp_f32
    float r = __builtin_amdgcn_rcpf(e + 1.0f);     // v_add + v_rcp_f32
    return 1.0f - 2.0f * r;                        // v_fma
}

__device__ __forceinline__ float wave_max(float v) {
    #pragma unroll
    for (int off = 32; off > 0; off >>= 1)
        v = fmaxf(v, __shfl_xor(v, off, 64));
    return v;
}
__device__ __forceinline__ float wave_sum(float v) {
    #pragma unroll
    for (int off = 32; off > 0; off >>= 1)
        v += __shfl_xor(v, off, 64);
    return v;
}

// out[m][u] = sum_d in[m][d] * w[d][u].  One wave per row (u = lane).
__global__ void proj_kernel(const float* __restrict__ in, const float* __restrict__ w,
                            float* __restrict__ out, int M) {
    int u = threadIdx.x & 63;
    int m = blockIdx.x * 4 + (threadIdx.x >> 6);
    if (m >= M) return;
    const float* row = in + (size_t)m * DQ;
    float acc = 0.f;
    #pragma unroll 8
    for (int d = 0; d < DQ; ++d)
        acc = fmaf(row[d], w[d * UNITS + u], acc);
    out[(size_t)m * UNITS + u] = acc;
}

__global__ __launch_bounds__(256) void attn_kernel(
        const float* __restrict__ qproj,   // [B*TQ, UNITS]
        const float* __restrict__ kproj,   // [B*TV, UNITS]
        const float* __restrict__ value,   // [B, TV, DV]
        const float* __restrict__ scale,   // [UNITS]
        float* __restrict__ out_ctx,       // [B*TQ, DV]
        float* __restrict__ out_attn) {    // [B*TQ, TV]
    __shared__ float q_lds[QBLK][UNITS];
    __shared__ float scale_lds[UNITS];
    __shared__ float sc[QBLK][TV];         // scores -> attn (16 KB)
    __shared__ float red[4];

    const int tid  = threadIdx.x;
    const int lane = tid & 63;
    const int wid  = tid >> 6;
    const int b    = blockIdx.x / (TQ / QBLK);
    const int qt   = blockIdx.x % (TQ / QBLK);
    const int q0   = qt * QBLK;

    if (tid < QBLK * UNITS)
        q_lds[tid >> 6][tid & 63] =
            qproj[((size_t)(b * TQ + q0) + (tid >> 6)) * UNITS + (tid & 63)];
    if (tid < UNITS) scale_lds[tid] = scale[tid];
    __syncthreads();

    // ---- scores: each thread owns one v per 256-tile, k row in registers ----
    const float* kb = kproj + (size_t)b * TV * UNITS;
    for (int tile = 0; tile < TV / 256; ++tile) {
        int v = tile * 256 + tid;
        float kr[UNITS];
        const float4* krow = (const float4*)(kb + (size_t)v * UNITS);
        #pragma unroll
        for (int i = 0; i < UNITS / 4; ++i) {
            float4 t = krow[i];
            kr[4*i+0] = t.x; kr[4*i+1] = t.y; kr[4*i+2] = t.z; kr[4*i+3] = t.w;
        }
        #pragma unroll
        for (int q = 0; q < QBLK; ++q) {
            float acc = 0.f;
            #pragma unroll
            for (int u = 0; u < UNITS; ++u)
                acc = fmaf(scale_lds[u], tanh_fast(q_lds[q][u] + kr[u]), acc);
            sc[q][v] = acc;
        }
    }
    __syncthreads();

    // ---- softmax per q row + write attn ----
    for (int q = 0; q < QBLK; ++q) {
        float m = -1e30f;
        #pragma unroll
        for (int i = 0; i < TV / 256; ++i)
            m = fmaxf(m, sc[q][tid + i * 256]);
        m = wave_max(m);
        if (lane == 0) red[wid] = m;
        __syncthreads();
        m = fmaxf(fmaxf(red[0], red[1]), fmaxf(red[2], red[3]));
        __syncthreads();
        float e[TV / 256];
        float s = 0.f;
        #pragma unroll
        for (int i = 0; i < TV / 256; ++i) {
            e[i] = __expf(sc[q][tid + i * 256] - m);
            s += e[i];
        }
        s = wave_sum(s);
        if (lane == 0) red[wid] = s;
        __syncthreads();
        s = red[0] + red[1] + red[2] + red[3];
        float inv = 1.0f / s;
        float* arow = out_attn + (size_t)(b * TQ + q0 + q) * TV;
        #pragma unroll
        for (int i = 0; i < TV / 256; ++i) {
            float a = e[i] * inv;
            sc[q][tid + i * 256] = a;
            arow[tid + i * 256] = a;
        }
        __syncthreads();
    }

    // ---- context: thread d owns output column d, broadcast attn from LDS ----
    const float* vb = value + (size_t)b * TV * DV;
    const int d = tid;                     // DV == 256 == blockDim.x
    float acc[QBLK] = {};
    #pragma unroll 4
    for (int v = 0; v < TV; ++v) {
        float val = vb[(size_t)v * DV + d];
        #pragma unroll
        for (int q = 0; q < QBLK; ++q)
            acc[q] = fmaf(sc[q][v], val, acc[q]);
    }
    #pragma unroll
    for (int q = 0; q < QBLK; ++q)
        out_ctx[(size_t)(b * TQ + q0 + q) * DV + d] = acc[q];
}

extern "C" void kernel_launch(void* const* d_in, const int* in_sizes, int n_in,
                              void* d_out, int out_size, void* d_ws, size_t ws_size,
                              hipStream_t stream) {
    const float* query = (const float*)d_in[0];
    const float* value = (const float*)d_in[1];
    const float* w1    = (const float*)d_in[2];
    const float* w2    = (const float*)d_in[3];
    const float* scale = (const float*)d_in[4];

    float* out      = (float*)d_out;
    float* out_ctx  = out;                         // [B*TQ*DV]
    float* out_attn = out + (size_t)B * TQ * DV;   // [B*TQ*TV]

    float* qproj = (float*)d_ws;                   // B*TQ*UNITS floats
    float* kproj = qproj + (size_t)B * TQ * UNITS; // B*TV*UNITS floats

    proj_kernel<<<dim3(B * TQ / 4), 256, 0, stream>>>(query, w1, qproj, B * TQ);
    proj_kernel<<<dim3(B * TV / 4), 256, 0, stream>>>(value, w2, kproj, B * TV);
    attn_kernel<<<dim3(B * (TQ / QBLK)), 256, 0, stream>>>(qproj, kproj, value, scale,
                                                           out_ctx, out_attn);
}